// Round 1
// baseline (4020.344 us; speedup 1.0000x reference)
//
#include <hip/hip_runtime.h>

typedef unsigned short u16;
typedef __attribute__((ext_vector_type(8))) short bf16x8;
typedef __attribute__((ext_vector_type(4))) float f32x4;

__device__ __forceinline__ float bf2f(u16 u) {
  union { unsigned u; float f; } v; v.u = ((unsigned)u) << 16; return v.f;
}
__device__ __forceinline__ u16 f2bf(float f) {
  union { float f; unsigned u; } v; v.f = f;
  unsigned r = v.u + 0x7FFFu + ((v.u >> 16) & 1u);
  return (u16)(r >> 16);
}

// ---------------- scratch layout (bytes inside d_out scores region) ----------
// scores region = first 262,144,000 bytes of d_out; it is ONLY written by the
// final log_softmax kernel, so we use it as scratch for everything before that.
constexpr size_t OFF_WCAT  = 0;           // bf16 [32000][1536]  (98,304,000 B)
constexpr size_t OFF_GI0   = 98304000;    // f32  [2048][3072]   (25,165,824 B)
constexpr size_t OFF_GI1   = 123469824;   // f32  [2048][3072]
constexpr size_t OFF_XOUT  = 148635648;   // bf16 [2048][1536]  (h1 | emb)
constexpr size_t OFF_H0ALL = 154927104;   // bf16 [2048][1024]
constexpr size_t OFF_WIH0E = 159121408;   // bf16 [3072][512]
constexpr size_t OFF_WHH0  = 162267136;   // bf16 [3072][1024]
constexpr size_t OFF_WIH1  = 168558592;   // bf16 [3072][1024]
constexpr size_t OFF_WHH1  = 174850048;   // bf16 [3072][1024]
constexpr size_t OFF_BASE0 = 181141504;   // f32  [16][3072]  b_ih0 + syn_z@Wsyn.T
constexpr size_t OFF_BASEO = 181338112;   // f32  [16][32000] b_out + sem_z@Wsem.T
constexpr size_t OFF_H0F   = 183386112;   // f32  2 x [16][1024] ping-pong
constexpr size_t OFF_H1F   = 183517184;   // f32  2 x [16][1024]
constexpr size_t OFF_H0IBF = 183648256;   // bf16 [16][1024] initial h0
constexpr size_t OFF_H1IBF = 183681024;   // bf16 [16][1024] initial h1
// real outputs
constexpr size_t OFF_HIDF  = 262144000;   // f32 [2][16][1024]
constexpr size_t OFF_LAST  = 262275072;   // f32 [16][1024]
constexpr size_t OFF_LOGIT = 262340608;   // f32 [2048][32000]

// ---------------- fp32 -> bf16 2D convert ------------------------------------
__global__ __launch_bounds__(256) void conv_bf16_k(
    const float* __restrict__ src, u16* __restrict__ dst,
    int rows, int cols8, int sld, int soff, int dld, int doff) {
  int t = blockIdx.x * 256 + threadIdx.x;
  if (t >= rows * cols8) return;
  int r = t / cols8, c = (t - r * cols8) * 8;
  const float* s = src + (size_t)r * sld + soff + c;
  float4 a = *(const float4*)s;
  float4 b = *(const float4*)(s + 4);
  bf16x8 o;
  o[0] = (short)f2bf(a.x); o[1] = (short)f2bf(a.y);
  o[2] = (short)f2bf(a.z); o[3] = (short)f2bf(a.w);
  o[4] = (short)f2bf(b.x); o[5] = (short)f2bf(b.y);
  o[6] = (short)f2bf(b.z); o[7] = (short)f2bf(b.w);
  *(bf16x8*)(dst + (size_t)r * dld + doff + c) = o;
}

// ---------------- embedding gather -> bf16 into XOUT[:,1024:1536] ------------
__global__ __launch_bounds__(256) void gather_emb_k(
    const int* __restrict__ seq, const float* __restrict__ table,
    u16* __restrict__ xout) {
  int t0 = blockIdx.x * 256 + threadIdx.x;  // 2048 rows * 64 chunks
  int tb = t0 >> 6, c = (t0 & 63) * 8;
  int tt = tb >> 4, b = tb & 15;
  int tok = seq[b * 128 + tt];              // input_seq is [B=16][T=128]
  const float* s = table + (size_t)tok * 512 + c;
  float4 a = *(const float4*)s;
  float4 bb = *(const float4*)(s + 4);
  bf16x8 o;
  o[0] = (short)f2bf(a.x);  o[1] = (short)f2bf(a.y);
  o[2] = (short)f2bf(a.z);  o[3] = (short)f2bf(a.w);
  o[4] = (short)f2bf(bb.x); o[5] = (short)f2bf(bb.y);
  o[6] = (short)f2bf(bb.z); o[7] = (short)f2bf(bb.w);
  *(bf16x8*)(xout + (size_t)tb * 1536 + 1024 + c) = o;
}

// ---------------- base0[b][j] = b_ih0[j] + syn_z[b] . W_ih0[j,512:1536] ------
__global__ __launch_bounds__(256) void base_syn_k(
    const float* __restrict__ syn, const float* __restrict__ Wih0,
    const float* __restrict__ bih0, float* __restrict__ out) {
  int j = blockIdx.x * 256 + threadIdx.x;   // 3072
  int b = blockIdx.y;                       // 16
  const float* w = Wih0 + (size_t)j * 1536 + 512;
  const float* sy = syn + b * 1024;
  float acc = bih0[j];
  for (int k = 0; k < 1024; k += 4) {
    float4 wv = *(const float4*)(w + k);
    float4 sv = *(const float4*)(sy + k);
    acc += wv.x * sv.x + wv.y * sv.y + wv.z * sv.z + wv.w * sv.w;
  }
  out[b * 3072 + j] = acc;
}

// ---------------- baseo[b][v] = b_out[v] + sem_z[b] . W_out[v,1024:2048] -----
__global__ __launch_bounds__(256) void base_out_k(
    const float* __restrict__ sem, const float* __restrict__ Wout,
    const float* __restrict__ bout, float* __restrict__ out) {
  int v = blockIdx.x * 256 + threadIdx.x;   // 32000
  int b = blockIdx.y;                       // 16
  const float* w = Wout + (size_t)v * 2560 + 1024;
  const float* se = sem + b * 1024;
  float acc = bout[v];
  for (int k = 0; k < 1024; k += 4) {
    float4 wv = *(const float4*)(w + k);
    float4 sv = *(const float4*)(se + k);
    acc += wv.x * sv.x + wv.y * sv.y + wv.z * sv.z + wv.w * sv.w;
  }
  out[b * 32000 + v] = acc;
}

// ---------------- init h buffers ---------------------------------------------
__global__ __launch_bounds__(256) void init_h_k(
    const float* __restrict__ hidden, float* __restrict__ h0,
    float* __restrict__ h1, u16* __restrict__ h0b, u16* __restrict__ h1b) {
  int i = blockIdx.x * 256 + threadIdx.x;   // 16384
  float v0 = hidden[i], v1 = hidden[16384 + i];
  h0[i] = v0; h1[i] = v1;
  h0b[i] = f2bf(v0); h1b[i] = f2bf(v1);
}

// ---------------- final hidden write -----------------------------------------
__global__ __launch_bounds__(256) void write_hidden_k(
    const float* __restrict__ h0, const float* __restrict__ h1,
    float* __restrict__ hidf, float* __restrict__ last) {
  int i = blockIdx.x * 256 + threadIdx.x;   // 16384
  float a = h0[i], b = h1[i];
  hidf[i] = a; hidf[16384 + i] = b; last[i] = b;
}

// ---------------- GRU step: gh = h@Whh.T ; gates ; h' ------------------------
// grid 256 blocks x 256 thr; wave = one j; lanes: b = lane&15, s = lane>>4
__global__ __launch_bounds__(256) void gru_step_k(
    const float* __restrict__ hin, const u16* __restrict__ hin_bf, int ibst,
    float* __restrict__ hout, u16* __restrict__ hbf_out, int obst,
    const float* __restrict__ gi, const u16* __restrict__ Whh,
    const float* __restrict__ bhh) {
  int tid = threadIdx.x;
  int lane = tid & 63;
  int b = lane & 15;
  int s = lane >> 4;                       // 0..3 (k-slice)
  int j = blockIdx.x * 4 + (tid >> 6);     // 0..1023
  float pr = 0.f, pz = 0.f, pn = 0.f;
  const u16* hrow = hin_bf + (size_t)b * ibst;
  const u16* wr = Whh + (size_t)j * 1024;
  const u16* wz = wr + 1024 * 1024;
  const u16* wn = wz + 1024 * 1024;
#pragma unroll 4
  for (int i = 0; i < 32; ++i) {
    int k = s * 8 + i * 32;
    bf16x8 hv = *(const bf16x8*)(hrow + k);
    bf16x8 w0 = *(const bf16x8*)(wr + k);
    bf16x8 w1 = *(const bf16x8*)(wz + k);
    bf16x8 w2 = *(const bf16x8*)(wn + k);
#pragma unroll
    for (int e = 0; e < 8; ++e) {
      float h = bf2f((u16)hv[e]);
      pr += bf2f((u16)w0[e]) * h;
      pz += bf2f((u16)w1[e]) * h;
      pn += bf2f((u16)w2[e]) * h;
    }
  }
  pr += __shfl_xor(pr, 16); pr += __shfl_xor(pr, 32);
  pz += __shfl_xor(pz, 16); pz += __shfl_xor(pz, 32);
  pn += __shfl_xor(pn, 16); pn += __shfl_xor(pn, 32);
  if (s == 0) {
    const float* gib = gi + b * 3072;
    float ir = gib[j], iz = gib[1024 + j], in_ = gib[2048 + j];
    float hr = pr + bhh[j], hz = pz + bhh[1024 + j], hn = pn + bhh[2048 + j];
    float r = 1.f / (1.f + expf(-(ir + hr)));
    float z = 1.f / (1.f + expf(-(iz + hz)));
    float n = tanhf(in_ + r * hn);
    float hprev = hin[b * 1024 + j];
    float hnew = (1.f - z) * n + z * hprev;
    hout[b * 1024 + j] = hnew;
    hbf_out[(size_t)b * obst + j] = f2bf(hnew);
  }
}

// ---------------- bf16 MFMA GEMM: C[M,N] = A[M,K] @ B[N,K].T (+ add) ---------
// MODE 0: none; 1: add[(row&15)*N + col]; 2: add[col]
template <int MODE>
__global__ __launch_bounds__(256) void gemm_bt_k(
    const u16* __restrict__ A, int lda, const u16* __restrict__ Bw, int ldb,
    float* __restrict__ C, int ldc, const float* __restrict__ add,
    int N, int K) {
  __shared__ u16 Asm_[128 * 32];
  __shared__ u16 Bsm_[128 * 32];
  const int m0 = blockIdx.x * 128, n0 = blockIdx.y * 128;
  const int tid = threadIdx.x, wave = tid >> 6, lane = tid & 63;
  const int wm = (wave >> 1) * 64, wn = (wave & 1) * 64;
  const int lrow = lane & 15, lk = (lane >> 4) * 8;
  f32x4 acc[4][4] = {};
  for (int k0 = 0; k0 < K; k0 += 32) {
    __syncthreads();  // previous tile fully consumed
#pragma unroll
    for (int q = 0; q < 2; ++q) {
      int c = (wave * 2 + q) * 64 + lane;
      int row = c >> 2, seg = c & 3;
      const u16* src = A + (size_t)(m0 + row) * lda + k0 + seg * 8;
      u16* dst = Asm_ + (wave * 2 + q) * 512;  // wave-uniform base
      __builtin_amdgcn_global_load_lds(
          (const __attribute__((address_space(1))) void*)src,
          (__attribute__((address_space(3))) void*)dst, 16, 0, 0);
    }
#pragma unroll
    for (int q = 0; q < 2; ++q) {
      int c = (wave * 2 + q) * 64 + lane;
      int row = c >> 2, seg = c & 3;
      const u16* src = Bw + (size_t)(n0 + row) * ldb + k0 + seg * 8;
      u16* dst = Bsm_ + (wave * 2 + q) * 512;
      __builtin_amdgcn_global_load_lds(
          (const __attribute__((address_space(1))) void*)src,
          (__attribute__((address_space(3))) void*)dst, 16, 0, 0);
    }
    asm volatile("s_waitcnt vmcnt(0)" ::: "memory");
    __syncthreads();
    bf16x8 af[4], bfr[4];
#pragma unroll
    for (int i = 0; i < 4; ++i) {
      af[i]  = *(const bf16x8*)(Asm_ + (wm + i * 16 + lrow) * 32 + lk);
      bfr[i] = *(const bf16x8*)(Bsm_ + (wn + i * 16 + lrow) * 32 + lk);
    }
#pragma unroll
    for (int i = 0; i < 4; ++i)
#pragma unroll
      for (int j = 0; j < 4; ++j)
        acc[i][j] = __builtin_amdgcn_mfma_f32_16x16x32_bf16(
            af[i], bfr[j], acc[i][j], 0, 0, 0);
  }
  const int lr4 = (lane >> 4) * 4;
#pragma unroll
  for (int i = 0; i < 4; ++i) {
#pragma unroll
    for (int j = 0; j < 4; ++j) {
      int gc = n0 + wn + j * 16 + lrow;
#pragma unroll
      for (int r = 0; r < 4; ++r) {
        int gr = m0 + wm + i * 16 + lr4 + r;
        float v = acc[i][j][r];
        if (MODE == 1) v += add[(gr & 15) * N + gc];
        else if (MODE == 2) v += add[gc];
        C[(size_t)gr * ldc + gc] = v;
      }
    }
  }
}

// ---------------- row-wise log_softmax (rows of 32000) -----------------------
__global__ __launch_bounds__(256) void log_softmax_k(
    const float* __restrict__ logits, float* __restrict__ scores) {
  int row = blockIdx.x;
  const float* x = logits + (size_t)row * 32000;
  float* y = scores + (size_t)row * 32000;
  __shared__ float red[8];
  int tid = threadIdx.x;
  float m = -3.4e38f;
  for (int idx = tid * 4; idx < 32000; idx += 1024) {
    float4 v = *(const float4*)(x + idx);
    m = fmaxf(m, fmaxf(fmaxf(v.x, v.y), fmaxf(v.z, v.w)));
  }
  for (int off = 32; off; off >>= 1) m = fmaxf(m, __shfl_xor(m, off));
  if ((tid & 63) == 0) red[tid >> 6] = m;
  __syncthreads();
  m = fmaxf(fmaxf(red[0], red[1]), fmaxf(red[2], red[3]));
  float s = 0.f;
  for (int idx = tid * 4; idx < 32000; idx += 1024) {
    float4 v = *(const float4*)(x + idx);
    s += __expf(v.x - m) + __expf(v.y - m) + __expf(v.z - m) + __expf(v.w - m);
  }
  for (int off = 32; off; off >>= 1) s += __shfl_xor(s, off);
  if ((tid & 63) == 0) red[4 + (tid >> 6)] = s;
  __syncthreads();
  s = red[4] + red[5] + red[6] + red[7];
  float lse = m + logf(s);
  for (int idx = tid * 4; idx < 32000; idx += 1024) {
    float4 v = *(const float4*)(x + idx);
    float4 o;
    o.x = v.x - lse; o.y = v.y - lse; o.z = v.z - lse; o.w = v.w - lse;
    *(float4*)(y + idx) = o;
  }
}

// =============================================================================
extern "C" void kernel_launch(void* const* d_in, const int* in_sizes, int n_in,
                              void* d_out, int out_size, void* d_ws,
                              size_t ws_size, hipStream_t stream) {
  const int*   seq    = (const int*)d_in[0];
  const float* sem    = (const float*)d_in[2];
  const float* syn    = (const float*)d_in[3];
  const float* hidden = (const float*)d_in[4];
  const float* table  = (const float*)d_in[5];
  const float* Wih0   = (const float*)d_in[6];
  const float* Whh0   = (const float*)d_in[7];
  const float* bih0   = (const float*)d_in[8];
  const float* bhh0   = (const float*)d_in[9];
  const float* Wih1   = (const float*)d_in[10];
  const float* Whh1   = (const float*)d_in[11];
  const float* bih1   = (const float*)d_in[12];
  const float* bhh1   = (const float*)d_in[13];
  const float* Wout   = (const float*)d_in[14];
  const float* bout   = (const float*)d_in[15];

  char* base = (char*)d_out;
  float* scores   = (float*)base;
  u16*   WCAT     = (u16*)(base + OFF_WCAT);
  float* GI0      = (float*)(base + OFF_GI0);
  float* GI1      = (float*)(base + OFF_GI1);
  u16*   XOUT     = (u16*)(base + OFF_XOUT);
  u16*   H0ALL    = (u16*)(base + OFF_H0ALL);
  u16*   WIH0E    = (u16*)(base + OFF_WIH0E);
  u16*   WHH0B    = (u16*)(base + OFF_WHH0);
  u16*   WIH1B    = (u16*)(base + OFF_WIH1);
  u16*   WHH1B    = (u16*)(base + OFF_WHH1);
  float* BASE0    = (float*)(base + OFF_BASE0);
  float* BASEO    = (float*)(base + OFF_BASEO);
  float* H0F      = (float*)(base + OFF_H0F);   // 2 x 16384 f32
  float* H1F      = (float*)(base + OFF_H1F);
  u16*   H0IBF    = (u16*)(base + OFF_H0IBF);
  u16*   H1IBF    = (u16*)(base + OFF_H1IBF);
  float* hidf     = (float*)(base + OFF_HIDF);
  float* last     = (float*)(base + OFF_LAST);
  float* logits   = (float*)(base + OFF_LOGIT);

  // --- weight conversions to bf16 ---
  conv_bf16_k<<<16000, 256, 0, stream>>>(Wout, WCAT, 32000, 128, 2560, 0, 1536, 0);
  conv_bf16_k<<<8000, 256, 0, stream>>>(Wout, WCAT, 32000, 64, 2560, 2048, 1536, 1024);
  conv_bf16_k<<<768, 256, 0, stream>>>(Wih0, WIH0E, 3072, 64, 1536, 0, 512, 0);
  conv_bf16_k<<<1536, 256, 0, stream>>>(Whh0, WHH0B, 3072, 128, 1024, 0, 1024, 0);
  conv_bf16_k<<<1536, 256, 0, stream>>>(Wih1, WIH1B, 3072, 128, 1024, 0, 1024, 0);
  conv_bf16_k<<<1536, 256, 0, stream>>>(Whh1, WHH1B, 3072, 128, 1024, 0, 1024, 0);

  // --- embeddings + time-invariant bases ---
  gather_emb_k<<<512, 256, 0, stream>>>(seq, table, XOUT);
  base_syn_k<<<dim3(12, 16), 256, 0, stream>>>(syn, Wih0, bih0, BASE0);
  base_out_k<<<dim3(125, 16), 256, 0, stream>>>(sem, Wout, bout, BASEO);

  // --- gi0 for all t: embs @ Wih0e.T + base0 ---
  gemm_bt_k<1><<<dim3(16, 24), 256, 0, stream>>>(
      XOUT + 1024, 1536, WIH0E, 512, GI0, 3072, BASE0, 3072, 512);

  // --- init hidden ---
  init_h_k<<<64, 256, 0, stream>>>(hidden, H0F, H1F, H0IBF, H1IBF);

  // --- layer-0 recurrence ---
  for (int t = 0; t < 128; ++t) {
    const float* hin = H0F + (t & 1) * 16384;
    float* hout = H0F + ((t + 1) & 1) * 16384;
    const u16* hbfin = (t == 0) ? H0IBF : (H0ALL + (size_t)(t - 1) * 16 * 1024);
    gru_step_k<<<256, 256, 0, stream>>>(
        hin, hbfin, 1024, hout, H0ALL + (size_t)t * 16 * 1024, 1024,
        GI0 + (size_t)t * 16 * 3072, WHH0B, bhh0);
  }

  // --- gi1 for all t: h0_all @ Wih1.T + b_ih1 ---
  gemm_bt_k<2><<<dim3(16, 24), 256, 0, stream>>>(
      H0ALL, 1024, WIH1B, 1024, GI1, 3072, bih1, 3072, 1024);

  // --- layer-1 recurrence (h1 bf16 lands in XOUT[:,0:1024]) ---
  for (int t = 0; t < 128; ++t) {
    const float* hin = H1F + (t & 1) * 16384;
    float* hout = H1F + ((t + 1) & 1) * 16384;
    const u16* hbfin = (t == 0) ? H1IBF : (XOUT + (size_t)(t - 1) * 16 * 1536);
    int ibst = (t == 0) ? 1024 : 1536;
    gru_step_k<<<256, 256, 0, stream>>>(
        hin, hbfin, ibst, hout, XOUT + (size_t)t * 16 * 1536, 1536,
        GI1 + (size_t)t * 16 * 3072, WHH1B, bhh1);
  }

  // --- hidden outputs (final state is in buffer 0 after 128 steps) ---
  write_hidden_k<<<64, 256, 0, stream>>>(H0F, H1F, hidf, last);

  // --- logits = XOUT @ WCAT.T + baseo  -> d_out logits region ---
  gemm_bt_k<1><<<dim3(16, 250), 256, 0, stream>>>(
      XOUT, 1536, WCAT, 1536, logits, 32000, BASEO, 32000, 1536);

  // --- scores = log_softmax(logits) -> d_out scores region (last writer) ---
  log_softmax_k<<<2048, 256, 0, stream>>>(logits, scores);
}